// Round 9
// baseline (241.043 us; speedup 1.0000x reference)
//
#include <hip/hip_runtime.h>

// MHA: B=4, S=1024, D=1024, H=16, DK=64
// prep (cvt+mask[b][kt][q]) -> fused QKV GEMM (global_load_lds, XCD-grouped,
// lb(256,3)) -> flash attn (no-max softmax, dbuf K/V, 1 barrier/kt) -> out GEMM.

typedef __attribute__((ext_vector_type(8))) short short8;
typedef __attribute__((ext_vector_type(4))) float f32x4;
typedef __attribute__((ext_vector_type(4))) unsigned short u16x4;
typedef __attribute__((ext_vector_type(4))) unsigned long long u64x4;
typedef unsigned short u16;
typedef unsigned long long u64;

#define SCALE_Q 0.180336880f  // 0.125 * log2(e); folded into Q at projection

__device__ __forceinline__ u16 f2bf(float f) {  // RNE
    unsigned u = __float_as_uint(f);
    return (u16)((u + 0x7FFFu + ((u >> 16) & 1u)) >> 16);
}
__device__ __forceinline__ u16 f2bf_fast(float f) {  // round-half-up, 2 ops
    return (u16)((__float_as_uint(f) + 0x8000u) >> 16);
}

// async global->LDS, 16B per lane; LDS dest is wave-uniform base + lane*16
__device__ __forceinline__ void gl_lds16(const u16* g, u16* l) {
    __builtin_amdgcn_global_load_lds(
        (__attribute__((address_space(1))) void*)g,
        (__attribute__((address_space(3))) void*)l, 16, 0, 0);
}

// ---------------- fused prep: 7x f32->bf16 cvt + mask->bits ----------------
__global__ __launch_bounds__(256) void prep(
    const float* __restrict__ q, const float* __restrict__ k,
    const float* __restrict__ v, const float* __restrict__ wq,
    const float* __restrict__ wk, const float* __restrict__ wv,
    const float* __restrict__ wo, const int* __restrict__ mask,
    u16* __restrict__ xq, u16* __restrict__ xk, u16* __restrict__ xv,
    u16* __restrict__ wqb, u16* __restrict__ wkb, u16* __restrict__ wvb,
    u16* __restrict__ wob, u64* __restrict__ bits) {
    int bid = blockIdx.x;
    if (bid < 16384) {
        const float* src; u16* dst; int i;
        if (bid < 12288) {
            int chunk = bid >> 12;
            int off = bid & 4095;
            src = (chunk == 0) ? q : ((chunk == 1) ? k : v);
            dst = (chunk == 0) ? xq : ((chunk == 1) ? xk : xv);
            i = off * 256 + threadIdx.x;
        } else {
            int wb = bid - 12288;
            int chunk = wb >> 10;
            int off = wb & 1023;
            src = (chunk == 0) ? wq : ((chunk == 1) ? wk : ((chunk == 2) ? wv : wo));
            dst = (chunk == 0) ? wqb : ((chunk == 1) ? wkb : ((chunk == 2) ? wvb : wob));
            i = off * 256 + threadIdx.x;
        }
        f32x4 val = ((const f32x4*)src)[i];
        u16x4 r;
        r.x = f2bf(val.x); r.y = f2bf(val.y); r.z = f2bf(val.z); r.w = f2bf(val.w);
        ((u16x4*)dst)[i] = r;
    } else {
        int mb = bid - 16384;   // 0..4095
        int wid = threadIdx.x >> 6, lane = threadIdx.x & 63;
        int base = mb * 1024 + wid * 256;   // int index into mask
        int b = mb >> 10, qrow = mb & 1023;
        #pragma unroll
        for (int j = 0; j < 4; ++j) {
            u64 bal = __ballot(mask[base + j * 64 + lane] != 0);
            int kt = wid * 4 + j;
            // transposed layout: bits[b][kt][q]
            if (lane == 0) bits[(size_t)(b * 16 + kt) * 1024 + qrow] = bal;
        }
    }
}

// ---------------- fused QKV projection GEMM (128x128, global_load_lds) ------
// 1-D grid 768, id = n*96 + p*32 + m -> same-A-tile blocks congruent mod 8.
// p=0 -> Q*scale [B,H,S,DK]; p=1 -> K [B,H,S,DK]; p=2 -> V^T [B,H,DK,S]
__global__ __launch_bounds__(256, 3) void gemm_qkv(
    const u16* __restrict__ Aq, const u16* __restrict__ Ak, const u16* __restrict__ Av,
    const u16* __restrict__ Wq, const u16* __restrict__ Wk, const u16* __restrict__ Wv,
    const float* __restrict__ bq, const float* __restrict__ bk, const float* __restrict__ bv,
    u16* __restrict__ Qo, u16* __restrict__ Ko, u16* __restrict__ VTo) {
    __shared__ __align__(16) u16 As[128 * 64];
    __shared__ __align__(16) u16 Bs[128 * 64];
    const int id = blockIdx.x;
    const int n0 = (id / 96) * 128;
    const int pm = id % 96;
    const int p = pm >> 5;
    const int m0 = (pm & 31) * 128;
    const u16* A = (p == 0) ? Aq : ((p == 1) ? Ak : Av);
    const u16* W = (p == 0) ? Wq : ((p == 1) ? Wk : Wv);
    const float* bias = (p == 0) ? bq : ((p == 1) ? bk : bv);

    const int t = threadIdx.x;
    const int lane = t & 63;
    const int wid = t >> 6;
    const int l15 = lane & 15;
    const int quad = lane >> 4;
    const int wm = (wid & 1) * 64;
    const int wn = (wid >> 1) * 64;
    const int r8 = lane >> 3, gr = lane & 7;

    f32x4 acc[4][4];
    #pragma unroll
    for (int i = 0; i < 4; ++i)
        #pragma unroll
        for (int j = 0; j < 4; ++j) acc[i][j] = (f32x4){0.f, 0.f, 0.f, 0.f};

    for (int kt = 0; kt < 1024; kt += 64) {
        __syncthreads();
        #pragma unroll
        for (int c = 0; c < 8; ++c) {
            int call = wid * 8 + c;
            if (call < 16) {
                int rb = call * 8;
                gl_lds16(&A[(size_t)(m0 + rb + r8) * 1024 + kt + gr * 8], &As[rb * 64]);
            } else {
                int rb = (call - 16) * 8;
                gl_lds16(&W[(size_t)(n0 + rb + r8) * 1024 + kt + gr * 8], &Bs[rb * 64]);
            }
        }
        __syncthreads();
        #pragma unroll
        for (int ks = 0; ks < 2; ++ks) {
            short8 af[4], bf[4];
            #pragma unroll
            for (int i = 0; i < 4; ++i) {
                af[i] = *(const short8*)&As[(wm + i * 16 + l15) * 64 + ks * 32 + quad * 8];
                bf[i] = *(const short8*)&Bs[(wn + i * 16 + l15) * 64 + ks * 32 + quad * 8];
            }
            #pragma unroll
            for (int mi = 0; mi < 4; ++mi)
                #pragma unroll
                for (int ni = 0; ni < 4; ++ni)
                    acc[mi][ni] = __builtin_amdgcn_mfma_f32_16x16x32_bf16(
                        af[mi], bf[ni], acc[mi][ni], 0, 0, 0);
        }
    }

    u16* dst01 = (p == 0) ? Qo : Ko;
    const float qs = (p == 0) ? SCALE_Q : 1.0f;
    #pragma unroll
    for (int mi = 0; mi < 4; ++mi) {
        #pragma unroll
        for (int ni = 0; ni < 4; ++ni) {
            int col = n0 + wn + ni * 16 + l15;  // 0..1023
            int h = col >> 6, dk = col & 63;
            float bcol = bias[col];
            if (p < 2) {
                #pragma unroll
                for (int r = 0; r < 4; ++r) {
                    int row = m0 + wm + mi * 16 + quad * 4 + r;
                    int bb = row >> 10, s = row & 1023;
                    dst01[(size_t)((bb * 16 + h) * 1024 + s) * 64 + dk] =
                        f2bf((acc[mi][ni][r] + bcol) * qs);
                }
            } else {
                int row0 = m0 + wm + mi * 16 + quad * 4;
                int bb = row0 >> 10, s0 = row0 & 1023;
                u64 pk = 0;
                #pragma unroll
                for (int r = 0; r < 4; ++r)
                    pk |= (u64)f2bf(acc[mi][ni][r] + bcol) << (16 * r);
                *(u64*)&VTo[(size_t)((bb * 16 + h) * 64 + dk) * 1024 + s0] = pk;
            }
        }
    }
}

// ---------------- output projection GEMM (64x128, global_load_lds) ----------
__global__ __launch_bounds__(256, 3) void gemm_out(
    const u16* __restrict__ X, const u16* __restrict__ Wo,
    const float* __restrict__ bo, float* __restrict__ out) {
    __shared__ __align__(16) u16 As[64 * 64];
    __shared__ __align__(16) u16 Bs[128 * 64];
    const int id = blockIdx.x;
    const int n0 = (id >> 6) * 128;
    const int m0 = (id & 63) * 64;
    const int t = threadIdx.x;
    const int lane = t & 63;
    const int wid = t >> 6;
    const int l15 = lane & 15;
    const int quad = lane >> 4;
    const int wm = (wid & 1) * 32;
    const int wn = (wid >> 1) * 64;
    const int r8 = lane >> 3, gr = lane & 7;

    f32x4 acc[2][4];
    #pragma unroll
    for (int i = 0; i < 2; ++i)
        #pragma unroll
        for (int j = 0; j < 4; ++j) acc[i][j] = (f32x4){0.f, 0.f, 0.f, 0.f};

    for (int kt = 0; kt < 1024; kt += 64) {
        __syncthreads();
        #pragma unroll
        for (int c = 0; c < 6; ++c) {
            int call = wid * 6 + c;
            if (call < 8) {
                int rb = call * 8;
                gl_lds16(&X[(size_t)(m0 + rb + r8) * 1024 + kt + gr * 8], &As[rb * 64]);
            } else {
                int rb = (call - 8) * 8;
                gl_lds16(&Wo[(size_t)(n0 + rb + r8) * 1024 + kt + gr * 8], &Bs[rb * 64]);
            }
        }
        __syncthreads();
        #pragma unroll
        for (int ks = 0; ks < 2; ++ks) {
            short8 af[2], bf[4];
            #pragma unroll
            for (int i = 0; i < 2; ++i)
                af[i] = *(const short8*)&As[(wm + i * 16 + l15) * 64 + ks * 32 + quad * 8];
            #pragma unroll
            for (int j = 0; j < 4; ++j)
                bf[j] = *(const short8*)&Bs[(wn + j * 16 + l15) * 64 + ks * 32 + quad * 8];
            #pragma unroll
            for (int mi = 0; mi < 2; ++mi)
                #pragma unroll
                for (int ni = 0; ni < 4; ++ni)
                    acc[mi][ni] = __builtin_amdgcn_mfma_f32_16x16x32_bf16(
                        af[mi], bf[ni], acc[mi][ni], 0, 0, 0);
        }
    }

    #pragma unroll
    for (int mi = 0; mi < 2; ++mi) {
        #pragma unroll
        for (int ni = 0; ni < 4; ++ni) {
            int col = n0 + wn + ni * 16 + l15;
            float bcol = bo[col];
            #pragma unroll
            for (int r = 0; r < 4; ++r) {
                int row = m0 + wm + mi * 16 + quad * 4 + r;
                out[(size_t)row * 1024 + col] = acc[mi][ni][r] + bcol;
            }
        }
    }
}

// ---------------- flash attention: dbuf K/V, 1 barrier/kt -------------------
// grid (16 q-tiles of 64, 16 heads, 4 batch), 4 waves x 16 q-rows.
// LDS: Ks[2]+Vs[2] (32KB) + Ps swizzled stride-64 (8KB) = 40KB -> 4 blocks/CU.
__global__ __launch_bounds__(256) void attn_kernel(
    const u16* __restrict__ Q, const u16* __restrict__ K, const u16* __restrict__ VT,
    const u64* __restrict__ mbits, u16* __restrict__ X) {
    __shared__ __align__(16) u16 Ks[2][64 * 64];
    __shared__ __align__(16) u16 Vs[2][64 * 64];
    __shared__ __align__(16) u16 Ps[4][16 * 64];  // per-wave, XOR-swizzled

    const int qt = blockIdx.x;
    const int h = blockIdx.y;
    const int b = blockIdx.z;
    const int t = threadIdx.x;
    const int lane = t & 63;
    const int wid = t >> 6;
    const int l15 = lane & 15;
    const int quad = lane >> 4;
    const int q0 = qt * 64;
    const int sr = t >> 3;   // 0..31 staging row
    const int sc = t & 7;    // 16B granule

    const size_t headoff = (size_t)(b * 16 + h) * 1024 * 64;
    const u16* Qh = Q + headoff;
    const u16* Kh = K + headoff;
    const u16* Vh = VT + headoff;  // [64][1024]

    // Q fragments straight to registers (row = q0 + wid*16 + l15)
    short8 qf[2];
    #pragma unroll
    for (int ks = 0; ks < 2; ++ks)
        qf[ks] = *(const short8*)&Qh[(size_t)(q0 + wid * 16 + l15) * 64 + ks * 32 + quad * 8];

    f32x4 o_acc[4];
    #pragma unroll
    for (int j = 0; j < 4; ++j) o_acc[j] = (f32x4){0.f, 0.f, 0.f, 0.f};
    float lacc[4] = {0.f, 0.f, 0.f, 0.f};

    // transposed mask: bits[b][kt][q]; this thread's 4 rows are contiguous
    const int qbase = q0 + wid * 16 + quad * 4;
    const u64* mbase = &mbits[(size_t)(b * 16) * 1024 + qbase];

    // prologue: tile 0 -> regs -> LDS buf0; then load tile 1 into regs
    short8 kpre[2], vpre[2];
    #pragma unroll
    for (int p = 0; p < 2; ++p) {
        int r = p * 32 + sr;
        kpre[p] = *(const short8*)&Kh[(size_t)r * 64 + sc * 8];
        vpre[p] = *(const short8*)&Vh[(size_t)r * 1024 + sc * 8];
    }
    #pragma unroll
    for (int p = 0; p < 2; ++p) {
        int r = p * 32 + sr;
        int gl = sc ^ (r & 7);
        *(short8*)&Ks[0][r * 64 + gl * 8] = kpre[p];
        *(short8*)&Vs[0][r * 64 + gl * 8] = vpre[p];
    }
    #pragma unroll
    for (int p = 0; p < 2; ++p) {
        int r = p * 32 + sr;
        kpre[p] = *(const short8*)&Kh[(size_t)(64 + r) * 64 + sc * 8];
        vpre[p] = *(const short8*)&Vh[(size_t)r * 1024 + 64 + sc * 8];
    }
    __syncthreads();

    for (int kt = 0; kt < 16; ++kt) {
        const int cur = kt & 1, nxt = cur ^ 1;
        // write staged regs (tile kt+1) into the buffer last read at kt-1
        if (kt < 15) {
            #pragma unroll
            for (int p = 0; p < 2; ++p) {
                int r = p * 32 + sr;
                int gl = sc ^ (r & 7);
                *(short8*)&Ks[nxt][r * 64 + gl * 8] = kpre[p];
                *(short8*)&Vs[nxt][r * 64 + gl * 8] = vpre[p];
            }
        }
        // issue global loads for tile kt+2
        if (kt < 14) {
            int kvn = (kt + 2) * 64;
            #pragma unroll
            for (int p = 0; p < 2; ++p) {
                int r = p * 32 + sr;
                kpre[p] = *(const short8*)&Kh[(size_t)(kvn + r) * 64 + sc * 8];
                vpre[p] = *(const short8*)&Vh[(size_t)r * 1024 + kvn + sc * 8];
            }
        }

        // S = Q K^T : wave computes 16 q-rows x 64 kv-cols
        f32x4 sacc[4];
        #pragma unroll
        for (int j = 0; j < 4; ++j) sacc[j] = (f32x4){0.f, 0.f, 0.f, 0.f};
        #pragma unroll
        for (int ks = 0; ks < 2; ++ks) {
            #pragma unroll
            for (int j = 0; j < 4; ++j) {
                int n = j * 16 + l15;
                short8 kf = *(const short8*)&Ks[cur][n * 64 + (((ks << 2) + quad) ^ (n & 7)) * 8];
                sacc[j] = __builtin_amdgcn_mfma_f32_16x16x32_bf16(qf[ks], kf, sacc[j], 0, 0, 0);
            }
        }

        // masked exp2, l accumulate, P -> per-wave swizzled LDS (bf16)
        u64x4 wv4 = *(const u64x4*)&mbase[(size_t)kt * 1024];
        #pragma unroll
        for (int r = 0; r < 4; ++r) {
            u64 w = wv4[r];
            unsigned t0 = (unsigned)w >> l15;
            unsigned t1 = (unsigned)(w >> 32) >> l15;
            int row = quad * 4 + r;
            #pragma unroll
            for (int ni = 0; ni < 4; ++ni) {
                unsigned bit = ((ni & 2) ? ((ni & 1) ? (t1 >> 16) : t1)
                                         : ((ni & 1) ? (t0 >> 16) : t0)) & 1u;
                float p = __builtin_amdgcn_exp2f(sacc[ni][r]);
                p = bit ? p : 0.f;
                lacc[r] += p;
                int g = (ni * 2 + (l15 >> 3)) ^ (row & 7);
                Ps[wid][row * 64 + g * 8 + (l15 & 7)] = f2bf_fast(p);
            }
        }

        // O += P V (P per-wave swizzled A-layout; V^T B-layout)
        #pragma unroll
        for (int ks = 0; ks < 2; ++ks) {
            short8 pf = *(const short8*)&Ps[wid][l15 * 64 + (((ks << 2) + quad) ^ (l15 & 7)) * 8];
            #pragma unroll
            for (int j = 0; j < 4; ++j) {
                int d = j * 16 + l15;
                short8 vf = *(const short8*)&Vs[cur][d * 64 + (((ks << 2) + quad) ^ (d & 7)) * 8];
                o_acc[j] = __builtin_amdgcn_mfma_f32_16x16x32_bf16(pf, vf, o_acc[j], 0, 0, 0);
            }
        }
        __syncthreads();  // all waves done with buf[cur]; writers may reuse it
    }

    // reduce l across the 16 lanes sharing each row, normalize, store
    #pragma unroll
    for (int r = 0; r < 4; ++r) {
        float l = lacc[r];
        l += __shfl_xor(l, 1);
        l += __shfl_xor(l, 2);
        l += __shfl_xor(l, 4);
        l += __shfl_xor(l, 8);
        float inv = 1.0f / l;
        int qrow = q0 + wid * 16 + quad * 4 + r;
        #pragma unroll
        for (int ni = 0; ni < 4; ++ni) {
            X[(size_t)(b * 1024 + qrow) * 1024 + h * 64 + ni * 16 + l15] =
                f2bf(o_acc[ni][r] * inv);
        }
    }
}

// ---------------- launch ----------------
extern "C" void kernel_launch(void* const* d_in, const int* in_sizes, int n_in,
                              void* d_out, int out_size, void* d_ws, size_t ws_size,
                              hipStream_t stream) {
    const float* query = (const float*)d_in[0];
    const float* key_ = (const float*)d_in[1];
    const float* value = (const float*)d_in[2];
    const int* mask = (const int*)d_in[3];
    const float* wq = (const float*)d_in[4];
    const float* bq = (const float*)d_in[5];
    const float* wk = (const float*)d_in[6];
    const float* bk = (const float*)d_in[7];
    const float* wv = (const float*)d_in[8];
    const float* bv = (const float*)d_in[9];
    const float* wo = (const float*)d_in[10];
    const float* bo = (const float*)d_in[11];
    float* out = (float*)d_out;

    char* ws = (char*)d_ws;
    const size_t XB = (size_t)4096 * 1024 * 2;  // 8 MB bf16 activation
    const size_t WB = (size_t)1024 * 1024 * 2;  // 2 MB bf16 weight
    u16* xq = (u16*)(ws);
    u16* xk = (u16*)(ws + XB);
    u16* xv = (u16*)(ws + 2 * XB);
    u16* wqb = (u16*)(ws + 3 * XB);
    u16* wkb = (u16*)(ws + 3 * XB + WB);
    u16* wvb = (u16*)(ws + 3 * XB + 2 * WB);
    u16* wob = (u16*)(ws + 3 * XB + 3 * WB);
    u16* Qb = (u16*)(ws + 3 * XB + 4 * WB);
    u16* Kb = (u16*)(ws + 4 * XB + 4 * WB);
    u16* VTb = (u16*)(ws + 5 * XB + 4 * WB);
    u64* bits = (u64*)(ws + 6 * XB + 4 * WB);
    u16* Xattn = xq;  // xq dead after gemm_qkv

    prep<<<20480, 256, 0, stream>>>(query, key_, value, wq, wk, wv, wo, mask,
                                    xq, xk, xv, wqb, wkb, wvb, wob, bits);
    gemm_qkv<<<768, 256, 0, stream>>>(xq, xk, xv, wqb, wkb, wvb,
                                      bq, bk, bv, Qb, Kb, VTb);
    attn_kernel<<<dim3(16, 16, 4), 256, 0, stream>>>(Qb, Kb, VTb, bits, Xattn);
    gemm_out<<<512, 256, 0, stream>>>(Xattn, wob, bo, out);
}

// Round 10
// 238.347 us; speedup vs baseline: 1.0113x; 1.0113x over previous
//
#include <hip/hip_runtime.h>

// MHA: B=4, S=1024, D=1024, H=16, DK=64
// prep (cvt+mask[b][kt][q]) -> fused QKV GEMM (global_load_lds, XCD-grouped)
// -> flash attn KV-SPLIT x2 (no-max softmax => partials additive; round-8
// two-barrier loop, 1-deep reg prefetch) -> merge (o0+o1)/(l0+l1) -> out GEMM.

typedef __attribute__((ext_vector_type(8))) short short8;
typedef __attribute__((ext_vector_type(4))) float f32x4;
typedef __attribute__((ext_vector_type(4))) unsigned short u16x4;
typedef __attribute__((ext_vector_type(4))) unsigned long long u64x4;
typedef unsigned short u16;
typedef unsigned long long u64;

#define SCALE_Q 0.180336880f  // 0.125 * log2(e); folded into Q at projection

__device__ __forceinline__ u16 f2bf(float f) {  // RNE
    unsigned u = __float_as_uint(f);
    return (u16)((u + 0x7FFFu + ((u >> 16) & 1u)) >> 16);
}
__device__ __forceinline__ u16 f2bf_fast(float f) {  // round-half-up
    return (u16)((__float_as_uint(f) + 0x8000u) >> 16);
}
__device__ __forceinline__ float bf2f(u16 v) {
    return __uint_as_float((unsigned)v << 16);
}

// async global->LDS, 16B per lane; LDS dest is wave-uniform base + lane*16
__device__ __forceinline__ void gl_lds16(const u16* g, u16* l) {
    __builtin_amdgcn_global_load_lds(
        (__attribute__((address_space(1))) void*)g,
        (__attribute__((address_space(3))) void*)l, 16, 0, 0);
}

// ---------------- fused prep: 7x f32->bf16 cvt + mask->bits ----------------
__global__ __launch_bounds__(256) void prep(
    const float* __restrict__ q, const float* __restrict__ k,
    const float* __restrict__ v, const float* __restrict__ wq,
    const float* __restrict__ wk, const float* __restrict__ wv,
    const float* __restrict__ wo, const int* __restrict__ mask,
    u16* __restrict__ xq, u16* __restrict__ xk, u16* __restrict__ xv,
    u16* __restrict__ wqb, u16* __restrict__ wkb, u16* __restrict__ wvb,
    u16* __restrict__ wob, u64* __restrict__ bits) {
    int bid = blockIdx.x;
    if (bid < 16384) {
        const float* src; u16* dst; int i;
        if (bid < 12288) {
            int chunk = bid >> 12;
            int off = bid & 4095;
            src = (chunk == 0) ? q : ((chunk == 1) ? k : v);
            dst = (chunk == 0) ? xq : ((chunk == 1) ? xk : xv);
            i = off * 256 + threadIdx.x;
        } else {
            int wb = bid - 12288;
            int chunk = wb >> 10;
            int off = wb & 1023;
            src = (chunk == 0) ? wq : ((chunk == 1) ? wk : ((chunk == 2) ? wv : wo));
            dst = (chunk == 0) ? wqb : ((chunk == 1) ? wkb : ((chunk == 2) ? wvb : wob));
            i = off * 256 + threadIdx.x;
        }
        f32x4 val = ((const f32x4*)src)[i];
        u16x4 r;
        r.x = f2bf(val.x); r.y = f2bf(val.y); r.z = f2bf(val.z); r.w = f2bf(val.w);
        ((u16x4*)dst)[i] = r;
    } else {
        int mb = bid - 16384;   // 0..4095
        int wid = threadIdx.x >> 6, lane = threadIdx.x & 63;
        int base = mb * 1024 + wid * 256;
        int b = mb >> 10, qrow = mb & 1023;
        #pragma unroll
        for (int j = 0; j < 4; ++j) {
            u64 bal = __ballot(mask[base + j * 64 + lane] != 0);
            int kt = wid * 4 + j;
            if (lane == 0) bits[(size_t)(b * 16 + kt) * 1024 + qrow] = bal;  // [b][kt][q]
        }
    }
}

// ---------------- fused QKV projection GEMM (128x128, global_load_lds) ------
// 1-D grid 768, id = n*96 + p*32 + m -> same-A-tile blocks congruent mod 8.
__global__ __launch_bounds__(256, 3) void gemm_qkv(
    const u16* __restrict__ Aq, const u16* __restrict__ Ak, const u16* __restrict__ Av,
    const u16* __restrict__ Wq, const u16* __restrict__ Wk, const u16* __restrict__ Wv,
    const float* __restrict__ bq, const float* __restrict__ bk, const float* __restrict__ bv,
    u16* __restrict__ Qo, u16* __restrict__ Ko, u16* __restrict__ VTo) {
    __shared__ __align__(16) u16 As[128 * 64];
    __shared__ __align__(16) u16 Bs[128 * 64];
    const int id = blockIdx.x;
    const int n0 = (id / 96) * 128;
    const int pm = id % 96;
    const int p = pm >> 5;
    const int m0 = (pm & 31) * 128;
    const u16* A = (p == 0) ? Aq : ((p == 1) ? Ak : Av);
    const u16* W = (p == 0) ? Wq : ((p == 1) ? Wk : Wv);
    const float* bias = (p == 0) ? bq : ((p == 1) ? bk : bv);

    const int t = threadIdx.x;
    const int lane = t & 63;
    const int wid = t >> 6;
    const int l15 = lane & 15;
    const int quad = lane >> 4;
    const int wm = (wid & 1) * 64;
    const int wn = (wid >> 1) * 64;
    const int r8 = lane >> 3, gr = lane & 7;

    f32x4 acc[4][4];
    #pragma unroll
    for (int i = 0; i < 4; ++i)
        #pragma unroll
        for (int j = 0; j < 4; ++j) acc[i][j] = (f32x4){0.f, 0.f, 0.f, 0.f};

    for (int kt = 0; kt < 1024; kt += 64) {
        __syncthreads();
        #pragma unroll
        for (int c = 0; c < 8; ++c) {
            int call = wid * 8 + c;
            if (call < 16) {
                int rb = call * 8;
                gl_lds16(&A[(size_t)(m0 + rb + r8) * 1024 + kt + gr * 8], &As[rb * 64]);
            } else {
                int rb = (call - 16) * 8;
                gl_lds16(&W[(size_t)(n0 + rb + r8) * 1024 + kt + gr * 8], &Bs[rb * 64]);
            }
        }
        __syncthreads();
        #pragma unroll
        for (int ks = 0; ks < 2; ++ks) {
            short8 af[4], bf[4];
            #pragma unroll
            for (int i = 0; i < 4; ++i) {
                af[i] = *(const short8*)&As[(wm + i * 16 + l15) * 64 + ks * 32 + quad * 8];
                bf[i] = *(const short8*)&Bs[(wn + i * 16 + l15) * 64 + ks * 32 + quad * 8];
            }
            #pragma unroll
            for (int mi = 0; mi < 4; ++mi)
                #pragma unroll
                for (int ni = 0; ni < 4; ++ni)
                    acc[mi][ni] = __builtin_amdgcn_mfma_f32_16x16x32_bf16(
                        af[mi], bf[ni], acc[mi][ni], 0, 0, 0);
        }
    }

    u16* dst01 = (p == 0) ? Qo : Ko;
    const float qs = (p == 0) ? SCALE_Q : 1.0f;
    #pragma unroll
    for (int mi = 0; mi < 4; ++mi) {
        #pragma unroll
        for (int ni = 0; ni < 4; ++ni) {
            int col = n0 + wn + ni * 16 + l15;  // 0..1023
            int h = col >> 6, dk = col & 63;
            float bcol = bias[col];
            if (p < 2) {
                #pragma unroll
                for (int r = 0; r < 4; ++r) {
                    int row = m0 + wm + mi * 16 + quad * 4 + r;
                    int bb = row >> 10, s = row & 1023;
                    dst01[(size_t)((bb * 16 + h) * 1024 + s) * 64 + dk] =
                        f2bf((acc[mi][ni][r] + bcol) * qs);
                }
            } else {
                int row0 = m0 + wm + mi * 16 + quad * 4;
                int bb = row0 >> 10, s0 = row0 & 1023;
                u64 pk = 0;
                #pragma unroll
                for (int r = 0; r < 4; ++r)
                    pk |= (u64)f2bf(acc[mi][ni][r] + bcol) << (16 * r);
                *(u64*)&VTo[(size_t)((bb * 16 + h) * 64 + dk) * 1024 + s0] = pk;
            }
        }
    }
}

// ---------------- output projection GEMM (64x128, global_load_lds) ----------
__global__ __launch_bounds__(256, 3) void gemm_out(
    const u16* __restrict__ X, const u16* __restrict__ Wo,
    const float* __restrict__ bo, float* __restrict__ out) {
    __shared__ __align__(16) u16 As[64 * 64];
    __shared__ __align__(16) u16 Bs[128 * 64];
    const int id = blockIdx.x;
    const int n0 = (id >> 6) * 128;
    const int m0 = (id & 63) * 64;
    const int t = threadIdx.x;
    const int lane = t & 63;
    const int wid = t >> 6;
    const int l15 = lane & 15;
    const int quad = lane >> 4;
    const int wm = (wid & 1) * 32;
    const int wn = (wid >> 1) * 64;
    const int r8 = lane >> 3, gr = lane & 7;

    f32x4 acc[2][4];
    #pragma unroll
    for (int i = 0; i < 2; ++i)
        #pragma unroll
        for (int j = 0; j < 4; ++j) acc[i][j] = (f32x4){0.f, 0.f, 0.f, 0.f};

    for (int kt = 0; kt < 1024; kt += 64) {
        __syncthreads();
        #pragma unroll
        for (int c = 0; c < 6; ++c) {
            int call = wid * 6 + c;
            if (call < 8) {
                int rb = call * 8;
                gl_lds16(&X[(size_t)(m0 + rb + r8) * 1024 + kt + gr * 8], &As[rb * 64]);
            } else {
                int rb = (call - 8) * 8;
                gl_lds16(&Wo[(size_t)(n0 + rb + r8) * 1024 + kt + gr * 8], &Bs[rb * 64]);
            }
        }
        __syncthreads();
        #pragma unroll
        for (int ks = 0; ks < 2; ++ks) {
            short8 af[2], bf[4];
            #pragma unroll
            for (int i = 0; i < 2; ++i)
                af[i] = *(const short8*)&As[(wm + i * 16 + l15) * 64 + ks * 32 + quad * 8];
            #pragma unroll
            for (int j = 0; j < 4; ++j)
                bf[j] = *(const short8*)&Bs[(wn + j * 16 + l15) * 64 + ks * 32 + quad * 8];
            #pragma unroll
            for (int mi = 0; mi < 2; ++mi)
                #pragma unroll
                for (int ni = 0; ni < 4; ++ni)
                    acc[mi][ni] = __builtin_amdgcn_mfma_f32_16x16x32_bf16(
                        af[mi], bf[ni], acc[mi][ni], 0, 0, 0);
        }
    }

    #pragma unroll
    for (int mi = 0; mi < 2; ++mi) {
        #pragma unroll
        for (int ni = 0; ni < 4; ++ni) {
            int col = n0 + wn + ni * 16 + l15;
            float bcol = bo[col];
            #pragma unroll
            for (int r = 0; r < 4; ++r) {
                int row = m0 + wm + mi * 16 + quad * 4 + r;
                out[(size_t)row * 1024 + col] = acc[mi][ni][r] + bcol;
            }
        }
    }
}

// ---------------- flash attention, KV-split x2 (round-8 loop) ---------------
// grid (16 qt, 16 h, 8 = b*2+half). Each block: 8 kv-tiles of its half.
// Writes unnormalized bf16 O-half [half][b][s][h*64+d] + fp32 l [half][b*16+h][s].
__global__ __launch_bounds__(256) void attn_kernel(
    const u16* __restrict__ Q, const u16* __restrict__ K, const u16* __restrict__ VT,
    const u64* __restrict__ mbits, u16* __restrict__ O, float* __restrict__ L) {
    __shared__ __align__(16) u16 Ks[64 * 64];
    __shared__ __align__(16) u16 Vs[64 * 64];
    __shared__ __align__(16) u16 Ps[4][16 * 72];  // per-wave P, stride 72

    const int qt = blockIdx.x;
    const int h = blockIdx.y;
    const int b = blockIdx.z >> 1;
    const int half = blockIdx.z & 1;
    const int t = threadIdx.x;
    const int lane = t & 63;
    const int wid = t >> 6;
    const int l15 = lane & 15;
    const int quad = lane >> 4;
    const int q0 = qt * 64;
    const int sr = t >> 3;
    const int sc = t & 7;
    const int ktg0 = half * 8;   // first global kv tile of this half

    const size_t headoff = (size_t)(b * 16 + h) * 1024 * 64;
    const u16* Qh = Q + headoff;
    const u16* Kh = K + headoff;
    const u16* Vh = VT + headoff;  // [64][1024]

    // Q fragments straight to registers (row = q0 + wid*16 + l15)
    short8 qf[2];
    #pragma unroll
    for (int ks = 0; ks < 2; ++ks)
        qf[ks] = *(const short8*)&Qh[(size_t)(q0 + wid * 16 + l15) * 64 + ks * 32 + quad * 8];

    f32x4 o_acc[4];
    #pragma unroll
    for (int j = 0; j < 4; ++j) o_acc[j] = (f32x4){0.f, 0.f, 0.f, 0.f};
    float lacc[4] = {0.f, 0.f, 0.f, 0.f};

    // transposed mask: bits[b][ktg][q]; this thread's 4 rows contiguous
    const int qbase = q0 + wid * 16 + quad * 4;
    const u64* mbase = &mbits[(size_t)(b * 16) * 1024 + qbase];

    // preload first kv tile of this half
    short8 kpre[2], vpre[2];
    #pragma unroll
    for (int p = 0; p < 2; ++p) {
        int r = p * 32 + sr;
        kpre[p] = *(const short8*)&Kh[(size_t)(ktg0 * 64 + r) * 64 + sc * 8];
        vpre[p] = *(const short8*)&Vh[(size_t)r * 1024 + ktg0 * 64 + sc * 8];
    }

    for (int kt = 0; kt < 8; ++kt) {
        __syncthreads();
        #pragma unroll
        for (int p = 0; p < 2; ++p) {
            int r = p * 32 + sr;
            int gl = sc ^ (r & 7);
            *(short8*)&Ks[r * 64 + gl * 8] = kpre[p];
            *(short8*)&Vs[r * 64 + gl * 8] = vpre[p];
        }
        __syncthreads();

        // prefetch next kv tile of this half
        if (kt < 7) {
            int kvn = (ktg0 + kt + 1) * 64;
            #pragma unroll
            for (int p = 0; p < 2; ++p) {
                int r = p * 32 + sr;
                kpre[p] = *(const short8*)&Kh[(size_t)(kvn + r) * 64 + sc * 8];
                vpre[p] = *(const short8*)&Vh[(size_t)r * 1024 + kvn + sc * 8];
            }
        }

        // S = Q K^T : wave computes 16 q-rows x 64 kv-cols
        f32x4 sacc[4];
        #pragma unroll
        for (int j = 0; j < 4; ++j) sacc[j] = (f32x4){0.f, 0.f, 0.f, 0.f};
        #pragma unroll
        for (int ks = 0; ks < 2; ++ks) {
            #pragma unroll
            for (int j = 0; j < 4; ++j) {
                int n = j * 16 + l15;
                short8 kf = *(const short8*)&Ks[n * 64 + (((ks << 2) + quad) ^ (n & 7)) * 8];
                sacc[j] = __builtin_amdgcn_mfma_f32_16x16x32_bf16(qf[ks], kf, sacc[j], 0, 0, 0);
            }
        }

        // masked exp2, l accumulate, P -> per-wave LDS (bf16)
        u64x4 wv4 = *(const u64x4*)&mbase[(size_t)(ktg0 + kt) * 1024];
        #pragma unroll
        for (int r = 0; r < 4; ++r) {
            u64 w = wv4[r];
            unsigned t0 = (unsigned)w >> l15;
            unsigned t1 = (unsigned)(w >> 32) >> l15;
            #pragma unroll
            for (int ni = 0; ni < 4; ++ni) {
                unsigned bit = ((ni & 2) ? ((ni & 1) ? (t1 >> 16) : t1)
                                         : ((ni & 1) ? (t0 >> 16) : t0)) & 1u;
                float p = __builtin_amdgcn_exp2f(sacc[ni][r]);
                p = bit ? p : 0.f;
                lacc[r] += p;
                Ps[wid][(quad * 4 + r) * 72 + ni * 16 + l15] = f2bf_fast(p);
            }
        }

        // O += P V (P per-wave LDS A-layout; V^T B-layout)
        #pragma unroll
        for (int ks = 0; ks < 2; ++ks) {
            short8 pf = *(const short8*)&Ps[wid][l15 * 72 + ks * 32 + quad * 8];
            #pragma unroll
            for (int j = 0; j < 4; ++j) {
                int d = j * 16 + l15;
                short8 vf = *(const short8*)&Vs[d * 64 + (((ks << 2) + quad) ^ (d & 7)) * 8];
                o_acc[j] = __builtin_amdgcn_mfma_f32_16x16x32_bf16(pf, vf, o_acc[j], 0, 0, 0);
            }
        }
    }

    // store unnormalized bf16 O-half + fp32 l-half (partials are additive)
    u16* Oh = O + (size_t)half * 4194304;
    float* Lh = L + (size_t)half * 65536;
    #pragma unroll
    for (int r = 0; r < 4; ++r) {
        float l = lacc[r];
        l += __shfl_xor(l, 1);
        l += __shfl_xor(l, 2);
        l += __shfl_xor(l, 4);
        l += __shfl_xor(l, 8);
        int qrow = qbase + r;
        if (l15 == 0) Lh[(size_t)(b * 16 + h) * 1024 + qrow] = l;
        #pragma unroll
        for (int ni = 0; ni < 4; ++ni) {
            Oh[(size_t)(b * 1024 + qrow) * 1024 + h * 64 + ni * 16 + l15] =
                f2bf(o_acc[ni][r]);
        }
    }
}

// ---------------- merge: X = (o0 + o1) / (l0 + l1), bf16 out ----------------
__global__ __launch_bounds__(256) void merge_halves(
    const u16* __restrict__ O, const float* __restrict__ L, u16* __restrict__ X) {
    int i = (blockIdx.x * 256 + threadIdx.x) * 8;   // elem index, 8 per thread
    int b = i >> 20, s = (i >> 10) & 1023, c = i & 1023, h = c >> 6;
    short8 o0 = *(const short8*)&O[i];
    short8 o1 = *(const short8*)&O[4194304 + i];
    size_t li = (size_t)(b * 16 + h) * 1024 + s;
    float inv = 1.0f / (L[li] + L[65536 + li]);
    short8 r;
    #pragma unroll
    for (int j = 0; j < 8; ++j) {
        float x = (bf2f((u16)o0[j]) + bf2f((u16)o1[j])) * inv;
        r[j] = (short)f2bf(x);
    }
    *(short8*)&X[i] = r;
}

// ---------------- launch ----------------
extern "C" void kernel_launch(void* const* d_in, const int* in_sizes, int n_in,
                              void* d_out, int out_size, void* d_ws, size_t ws_size,
                              hipStream_t stream) {
    const float* query = (const float*)d_in[0];
    const float* key_ = (const float*)d_in[1];
    const float* value = (const float*)d_in[2];
    const int* mask = (const int*)d_in[3];
    const float* wq = (const float*)d_in[4];
    const float* bq = (const float*)d_in[5];
    const float* wk = (const float*)d_in[6];
    const float* bk = (const float*)d_in[7];
    const float* wv = (const float*)d_in[8];
    const float* bv = (const float*)d_in[9];
    const float* wo = (const float*)d_in[10];
    const float* bo = (const float*)d_in[11];
    float* out = (float*)d_out;

    char* ws = (char*)d_ws;
    const size_t XB = (size_t)4096 * 1024 * 2;  // 8 MB bf16 activation
    const size_t WB = (size_t)1024 * 1024 * 2;  // 2 MB bf16 weight
    u16* xq = (u16*)(ws);
    u16* xk = (u16*)(ws + XB);        // after qkv: O-half 0
    u16* xv = (u16*)(ws + 2 * XB);    // after qkv: O-half 1
    u16* wqb = (u16*)(ws + 3 * XB);
    u16* wkb = (u16*)(ws + 3 * XB + WB);
    u16* wvb = (u16*)(ws + 3 * XB + 2 * WB);
    u16* wob = (u16*)(ws + 3 * XB + 3 * WB);
    u16* Qb = (u16*)(ws + 3 * XB + 4 * WB);
    u16* Kb = (u16*)(ws + 4 * XB + 4 * WB);
    u16* VTb = (u16*)(ws + 5 * XB + 4 * WB);
    u64* bits = (u64*)(ws + 6 * XB + 4 * WB);
    float* Lbuf = (float*)(ws + 6 * XB + 4 * WB + (512 << 10));
    u16* Opart = xk;    // 16 MB spanning xk+xv (dead after gemm_qkv)
    u16* Xattn = xq;    // xq dead after gemm_qkv

    prep<<<20480, 256, 0, stream>>>(query, key_, value, wq, wk, wv, wo, mask,
                                    xq, xk, xv, wqb, wkb, wvb, wob, bits);
    gemm_qkv<<<768, 256, 0, stream>>>(xq, xk, xv, wqb, wkb, wvb,
                                      bq, bk, bv, Qb, Kb, VTb);
    attn_kernel<<<dim3(16, 16, 8), 256, 0, stream>>>(Qb, Kb, VTb, bits, Opart, Lbuf);
    merge_halves<<<2048, 256, 0, stream>>>(Opart, Lbuf, Xattn);
    gemm_out<<<512, 256, 0, stream>>>(Xattn, wob, bo, out);
}

// Round 11
// 235.860 us; speedup vs baseline: 1.0220x; 1.0105x over previous
//
#include <hip/hip_runtime.h>

// MHA: B=4, S=1024, D=1024, H=16, DK=64
// prep (cvt+mask[b][kt][q]) -> fused QKV GEMM (global_load_lds with GLOBAL-side
// XOR swizzle -> conflict-free ds_read) -> flash attn KV-split x2 -> merge ->
// out GEMM (same swizzled staging).

typedef __attribute__((ext_vector_type(8))) short short8;
typedef __attribute__((ext_vector_type(4))) float f32x4;
typedef __attribute__((ext_vector_type(4))) unsigned short u16x4;
typedef __attribute__((ext_vector_type(4))) unsigned long long u64x4;
typedef unsigned short u16;
typedef unsigned long long u64;

#define SCALE_Q 0.180336880f  // 0.125 * log2(e); folded into Q at projection

__device__ __forceinline__ u16 f2bf(float f) {  // RNE
    unsigned u = __float_as_uint(f);
    return (u16)((u + 0x7FFFu + ((u >> 16) & 1u)) >> 16);
}
__device__ __forceinline__ u16 f2bf_fast(float f) {  // round-half-up
    return (u16)((__float_as_uint(f) + 0x8000u) >> 16);
}
__device__ __forceinline__ float bf2f(u16 v) {
    return __uint_as_float((unsigned)v << 16);
}

// async global->LDS, 16B per lane; LDS dest is wave-uniform base + lane*16
__device__ __forceinline__ void gl_lds16(const u16* g, u16* l) {
    __builtin_amdgcn_global_load_lds(
        (__attribute__((address_space(1))) void*)g,
        (__attribute__((address_space(3))) void*)l, 16, 0, 0);
}

// ---------------- fused prep: 7x f32->bf16 cvt + mask->bits ----------------
__global__ __launch_bounds__(256) void prep(
    const float* __restrict__ q, const float* __restrict__ k,
    const float* __restrict__ v, const float* __restrict__ wq,
    const float* __restrict__ wk, const float* __restrict__ wv,
    const float* __restrict__ wo, const int* __restrict__ mask,
    u16* __restrict__ xq, u16* __restrict__ xk, u16* __restrict__ xv,
    u16* __restrict__ wqb, u16* __restrict__ wkb, u16* __restrict__ wvb,
    u16* __restrict__ wob, u64* __restrict__ bits) {
    int bid = blockIdx.x;
    if (bid < 16384) {
        const float* src; u16* dst; int i;
        if (bid < 12288) {
            int chunk = bid >> 12;
            int off = bid & 4095;
            src = (chunk == 0) ? q : ((chunk == 1) ? k : v);
            dst = (chunk == 0) ? xq : ((chunk == 1) ? xk : xv);
            i = off * 256 + threadIdx.x;
        } else {
            int wb = bid - 12288;
            int chunk = wb >> 10;
            int off = wb & 1023;
            src = (chunk == 0) ? wq : ((chunk == 1) ? wk : ((chunk == 2) ? wv : wo));
            dst = (chunk == 0) ? wqb : ((chunk == 1) ? wkb : ((chunk == 2) ? wvb : wob));
            i = off * 256 + threadIdx.x;
        }
        f32x4 val = ((const f32x4*)src)[i];
        u16x4 r;
        r.x = f2bf(val.x); r.y = f2bf(val.y); r.z = f2bf(val.z); r.w = f2bf(val.w);
        ((u16x4*)dst)[i] = r;
    } else {
        int mb = bid - 16384;   // 0..4095
        int wid = threadIdx.x >> 6, lane = threadIdx.x & 63;
        int base = mb * 1024 + wid * 256;
        int b = mb >> 10, qrow = mb & 1023;
        #pragma unroll
        for (int j = 0; j < 4; ++j) {
            u64 bal = __ballot(mask[base + j * 64 + lane] != 0);
            int kt = wid * 4 + j;
            if (lane == 0) bits[(size_t)(b * 16 + kt) * 1024 + qrow] = bal;  // [b][kt][q]
        }
    }
}

// ---------------- fused QKV projection GEMM (128x128, swizzled staging) -----
// 1-D grid 768, id = n*96 + p*32 + m -> same-A-tile blocks congruent mod 8.
// Staging: lane (r8,gr) fetches global granule gr^r8 -> LDS holds
// A[row][g^(row&7)] -> conflict-free XOR reads (round-1 pattern).
__global__ __launch_bounds__(256, 3) void gemm_qkv(
    const u16* __restrict__ Aq, const u16* __restrict__ Ak, const u16* __restrict__ Av,
    const u16* __restrict__ Wq, const u16* __restrict__ Wk, const u16* __restrict__ Wv,
    const float* __restrict__ bq, const float* __restrict__ bk, const float* __restrict__ bv,
    u16* __restrict__ Qo, u16* __restrict__ Ko, u16* __restrict__ VTo) {
    __shared__ __align__(16) u16 As[128 * 64];
    __shared__ __align__(16) u16 Bs[128 * 64];
    const int id = blockIdx.x;
    const int n0 = (id / 96) * 128;
    const int pm = id % 96;
    const int p = pm >> 5;
    const int m0 = (pm & 31) * 128;
    const u16* A = (p == 0) ? Aq : ((p == 1) ? Ak : Av);
    const u16* W = (p == 0) ? Wq : ((p == 1) ? Wk : Wv);
    const float* bias = (p == 0) ? bq : ((p == 1) ? bk : bv);

    const int t = threadIdx.x;
    const int lane = t & 63;
    const int wid = t >> 6;
    const int l15 = lane & 15;
    const int quad = lane >> 4;
    const int wm = (wid & 1) * 64;
    const int wn = (wid >> 1) * 64;
    const int r8 = lane >> 3, gr = lane & 7;
    const int gsw = (gr ^ r8) * 8;   // swizzled global granule offset

    f32x4 acc[4][4];
    #pragma unroll
    for (int i = 0; i < 4; ++i)
        #pragma unroll
        for (int j = 0; j < 4; ++j) acc[i][j] = (f32x4){0.f, 0.f, 0.f, 0.f};

    for (int kt = 0; kt < 1024; kt += 64) {
        __syncthreads();
        #pragma unroll
        for (int c = 0; c < 8; ++c) {
            int call = wid * 8 + c;
            if (call < 16) {
                int rb = call * 8;
                gl_lds16(&A[(size_t)(m0 + rb + r8) * 1024 + kt + gsw], &As[rb * 64]);
            } else {
                int rb = (call - 16) * 8;
                gl_lds16(&W[(size_t)(n0 + rb + r8) * 1024 + kt + gsw], &Bs[rb * 64]);
            }
        }
        __syncthreads();
        #pragma unroll
        for (int ks = 0; ks < 2; ++ks) {
            short8 af[4], bf[4];
            #pragma unroll
            for (int i = 0; i < 4; ++i) {
                int mr = wm + i * 16 + l15;
                af[i] = *(const short8*)&As[mr * 64 + (((ks << 2) + quad) ^ (mr & 7)) * 8];
                int nr = wn + i * 16 + l15;
                bf[i] = *(const short8*)&Bs[nr * 64 + (((ks << 2) + quad) ^ (nr & 7)) * 8];
            }
            #pragma unroll
            for (int mi = 0; mi < 4; ++mi)
                #pragma unroll
                for (int ni = 0; ni < 4; ++ni)
                    acc[mi][ni] = __builtin_amdgcn_mfma_f32_16x16x32_bf16(
                        af[mi], bf[ni], acc[mi][ni], 0, 0, 0);
        }
    }

    u16* dst01 = (p == 0) ? Qo : Ko;
    const float qs = (p == 0) ? SCALE_Q : 1.0f;
    #pragma unroll
    for (int mi = 0; mi < 4; ++mi) {
        #pragma unroll
        for (int ni = 0; ni < 4; ++ni) {
            int col = n0 + wn + ni * 16 + l15;  // 0..1023
            int h = col >> 6, dk = col & 63;
            float bcol = bias[col];
            if (p < 2) {
                #pragma unroll
                for (int r = 0; r < 4; ++r) {
                    int row = m0 + wm + mi * 16 + quad * 4 + r;
                    int bb = row >> 10, s = row & 1023;
                    dst01[(size_t)((bb * 16 + h) * 1024 + s) * 64 + dk] =
                        f2bf((acc[mi][ni][r] + bcol) * qs);
                }
            } else {
                int row0 = m0 + wm + mi * 16 + quad * 4;
                int bb = row0 >> 10, s0 = row0 & 1023;
                u64 pk = 0;
                #pragma unroll
                for (int r = 0; r < 4; ++r)
                    pk |= (u64)f2bf(acc[mi][ni][r] + bcol) << (16 * r);
                *(u64*)&VTo[(size_t)((bb * 16 + h) * 64 + dk) * 1024 + s0] = pk;
            }
        }
    }
}

// ---------------- output projection GEMM (64x128, swizzled staging) ---------
__global__ __launch_bounds__(256, 3) void gemm_out(
    const u16* __restrict__ X, const u16* __restrict__ Wo,
    const float* __restrict__ bo, float* __restrict__ out) {
    __shared__ __align__(16) u16 As[64 * 64];
    __shared__ __align__(16) u16 Bs[128 * 64];
    const int id = blockIdx.x;
    const int n0 = (id >> 6) * 128;
    const int m0 = (id & 63) * 64;
    const int t = threadIdx.x;
    const int lane = t & 63;
    const int wid = t >> 6;
    const int l15 = lane & 15;
    const int quad = lane >> 4;
    const int wm = (wid & 1) * 32;
    const int wn = (wid >> 1) * 64;
    const int r8 = lane >> 3, gr = lane & 7;
    const int gsw = (gr ^ r8) * 8;

    f32x4 acc[2][4];
    #pragma unroll
    for (int i = 0; i < 2; ++i)
        #pragma unroll
        for (int j = 0; j < 4; ++j) acc[i][j] = (f32x4){0.f, 0.f, 0.f, 0.f};

    for (int kt = 0; kt < 1024; kt += 64) {
        __syncthreads();
        #pragma unroll
        for (int c = 0; c < 6; ++c) {
            int call = wid * 6 + c;
            if (call < 8) {
                int rb = call * 8;
                gl_lds16(&X[(size_t)(m0 + rb + r8) * 1024 + kt + gsw], &As[rb * 64]);
            } else {
                int rb = (call - 8) * 8;
                gl_lds16(&Wo[(size_t)(n0 + rb + r8) * 1024 + kt + gsw], &Bs[rb * 64]);
            }
        }
        __syncthreads();
        #pragma unroll
        for (int ks = 0; ks < 2; ++ks) {
            short8 af[2], bf[4];
            #pragma unroll
            for (int i = 0; i < 2; ++i) {
                int mr = wm + i * 16 + l15;
                af[i] = *(const short8*)&As[mr * 64 + (((ks << 2) + quad) ^ (mr & 7)) * 8];
            }
            #pragma unroll
            for (int j = 0; j < 4; ++j) {
                int nr = wn + j * 16 + l15;
                bf[j] = *(const short8*)&Bs[nr * 64 + (((ks << 2) + quad) ^ (nr & 7)) * 8];
            }
            #pragma unroll
            for (int mi = 0; mi < 2; ++mi)
                #pragma unroll
                for (int ni = 0; ni < 4; ++ni)
                    acc[mi][ni] = __builtin_amdgcn_mfma_f32_16x16x32_bf16(
                        af[mi], bf[ni], acc[mi][ni], 0, 0, 0);
        }
    }

    #pragma unroll
    for (int mi = 0; mi < 2; ++mi) {
        #pragma unroll
        for (int ni = 0; ni < 4; ++ni) {
            int col = n0 + wn + ni * 16 + l15;
            float bcol = bo[col];
            #pragma unroll
            for (int r = 0; r < 4; ++r) {
                int row = m0 + wm + mi * 16 + quad * 4 + r;
                out[(size_t)row * 1024 + col] = acc[mi][ni][r] + bcol;
            }
        }
    }
}

// ---------------- flash attention, KV-split x2 (round-8 loop) ---------------
// grid (16 qt, 16 h, 8 = b*2+half). Each block: 8 kv-tiles of its half.
// Writes unnormalized bf16 O-half [half][b][s][h*64+d] + fp32 l [half][b*16+h][s].
__global__ __launch_bounds__(256) void attn_kernel(
    const u16* __restrict__ Q, const u16* __restrict__ K, const u16* __restrict__ VT,
    const u64* __restrict__ mbits, u16* __restrict__ O, float* __restrict__ L) {
    __shared__ __align__(16) u16 Ks[64 * 64];
    __shared__ __align__(16) u16 Vs[64 * 64];
    __shared__ __align__(16) u16 Ps[4][16 * 72];  // per-wave P, stride 72

    const int qt = blockIdx.x;
    const int h = blockIdx.y;
    const int b = blockIdx.z >> 1;
    const int half = blockIdx.z & 1;
    const int t = threadIdx.x;
    const int lane = t & 63;
    const int wid = t >> 6;
    const int l15 = lane & 15;
    const int quad = lane >> 4;
    const int q0 = qt * 64;
    const int sr = t >> 3;
    const int sc = t & 7;
    const int ktg0 = half * 8;   // first global kv tile of this half

    const size_t headoff = (size_t)(b * 16 + h) * 1024 * 64;
    const u16* Qh = Q + headoff;
    const u16* Kh = K + headoff;
    const u16* Vh = VT + headoff;  // [64][1024]

    // Q fragments straight to registers (row = q0 + wid*16 + l15)
    short8 qf[2];
    #pragma unroll
    for (int ks = 0; ks < 2; ++ks)
        qf[ks] = *(const short8*)&Qh[(size_t)(q0 + wid * 16 + l15) * 64 + ks * 32 + quad * 8];

    f32x4 o_acc[4];
    #pragma unroll
    for (int j = 0; j < 4; ++j) o_acc[j] = (f32x4){0.f, 0.f, 0.f, 0.f};
    float lacc[4] = {0.f, 0.f, 0.f, 0.f};

    // transposed mask: bits[b][ktg][q]; this thread's 4 rows contiguous
    const int qbase = q0 + wid * 16 + quad * 4;
    const u64* mbase = &mbits[(size_t)(b * 16) * 1024 + qbase];

    // preload first kv tile of this half
    short8 kpre[2], vpre[2];
    #pragma unroll
    for (int p = 0; p < 2; ++p) {
        int r = p * 32 + sr;
        kpre[p] = *(const short8*)&Kh[(size_t)(ktg0 * 64 + r) * 64 + sc * 8];
        vpre[p] = *(const short8*)&Vh[(size_t)r * 1024 + ktg0 * 64 + sc * 8];
    }

    for (int kt = 0; kt < 8; ++kt) {
        __syncthreads();
        #pragma unroll
        for (int p = 0; p < 2; ++p) {
            int r = p * 32 + sr;
            int gl = sc ^ (r & 7);
            *(short8*)&Ks[r * 64 + gl * 8] = kpre[p];
            *(short8*)&Vs[r * 64 + gl * 8] = vpre[p];
        }
        __syncthreads();

        // prefetch next kv tile of this half
        if (kt < 7) {
            int kvn = (ktg0 + kt + 1) * 64;
            #pragma unroll
            for (int p = 0; p < 2; ++p) {
                int r = p * 32 + sr;
                kpre[p] = *(const short8*)&Kh[(size_t)(kvn + r) * 64 + sc * 8];
                vpre[p] = *(const short8*)&Vh[(size_t)r * 1024 + kvn + sc * 8];
            }
        }

        // S = Q K^T : wave computes 16 q-rows x 64 kv-cols
        f32x4 sacc[4];
        #pragma unroll
        for (int j = 0; j < 4; ++j) sacc[j] = (f32x4){0.f, 0.f, 0.f, 0.f};
        #pragma unroll
        for (int ks = 0; ks < 2; ++ks) {
            #pragma unroll
            for (int j = 0; j < 4; ++j) {
                int n = j * 16 + l15;
                short8 kf = *(const short8*)&Ks[n * 64 + (((ks << 2) + quad) ^ (n & 7)) * 8];
                sacc[j] = __builtin_amdgcn_mfma_f32_16x16x32_bf16(qf[ks], kf, sacc[j], 0, 0, 0);
            }
        }

        // masked exp2, l accumulate, P -> per-wave LDS (bf16)
        u64x4 wv4 = *(const u64x4*)&mbase[(size_t)(ktg0 + kt) * 1024];
        #pragma unroll
        for (int r = 0; r < 4; ++r) {
            u64 w = wv4[r];
            unsigned t0 = (unsigned)w >> l15;
            unsigned t1 = (unsigned)(w >> 32) >> l15;
            #pragma unroll
            for (int ni = 0; ni < 4; ++ni) {
                unsigned bit = ((ni & 2) ? ((ni & 1) ? (t1 >> 16) : t1)
                                         : ((ni & 1) ? (t0 >> 16) : t0)) & 1u;
                float p = __builtin_amdgcn_exp2f(sacc[ni][r]);
                p = bit ? p : 0.f;
                lacc[r] += p;
                Ps[wid][(quad * 4 + r) * 72 + ni * 16 + l15] = f2bf_fast(p);
            }
        }

        // O += P V (P per-wave LDS A-layout; V^T B-layout)
        #pragma unroll
        for (int ks = 0; ks < 2; ++ks) {
            short8 pf = *(const short8*)&Ps[wid][l15 * 72 + ks * 32 + quad * 8];
            #pragma unroll
            for (int j = 0; j < 4; ++j) {
                int d = j * 16 + l15;
                short8 vf = *(const short8*)&Vs[d * 64 + (((ks << 2) + quad) ^ (d & 7)) * 8];
                o_acc[j] = __builtin_amdgcn_mfma_f32_16x16x32_bf16(pf, vf, o_acc[j], 0, 0, 0);
            }
        }
    }

    // store unnormalized bf16 O-half + fp32 l-half (partials are additive)
    u16* Oh = O + (size_t)half * 4194304;
    float* Lh = L + (size_t)half * 65536;
    #pragma unroll
    for (int r = 0; r < 4; ++r) {
        float l = lacc[r];
        l += __shfl_xor(l, 1);
        l += __shfl_xor(l, 2);
        l += __shfl_xor(l, 4);
        l += __shfl_xor(l, 8);
        int qrow = qbase + r;
        if (l15 == 0) Lh[(size_t)(b * 16 + h) * 1024 + qrow] = l;
        #pragma unroll
        for (int ni = 0; ni < 4; ++ni) {
            Oh[(size_t)(b * 1024 + qrow) * 1024 + h * 64 + ni * 16 + l15] =
                f2bf(o_acc[ni][r]);
        }
    }
}

// ---------------- merge: X = (o0 + o1) / (l0 + l1), bf16 out ----------------
__global__ __launch_bounds__(256) void merge_halves(
    const u16* __restrict__ O, const float* __restrict__ L, u16* __restrict__ X) {
    int i = (blockIdx.x * 256 + threadIdx.x) * 8;   // elem index, 8 per thread
    int b = i >> 20, s = (i >> 10) & 1023, c = i & 1023, h = c >> 6;
    short8 o0 = *(const short8*)&O[i];
    short8 o1 = *(const short8*)&O[4194304 + i];
    size_t li = (size_t)(b * 16 + h) * 1024 + s;
    float inv = 1.0f / (L[li] + L[65536 + li]);
    short8 r;
    #pragma unroll
    for (int j = 0; j < 8; ++j) {
        float x = (bf2f((u16)o0[j]) + bf2f((u16)o1[j])) * inv;
        r[j] = (short)f2bf(x);
    }
    *(short8*)&X[i] = r;
}

// ---------------- launch ----------------
extern "C" void kernel_launch(void* const* d_in, const int* in_sizes, int n_in,
                              void* d_out, int out_size, void* d_ws, size_t ws_size,
                              hipStream_t stream) {
    const float* query = (const float*)d_in[0];
    const float* key_ = (const float*)d_in[1];
    const float* value = (const float*)d_in[2];
    const int* mask = (const int*)d_in[3];
    const float* wq = (const float*)d_in[4];
    const float* bq = (const float*)d_in[5];
    const float* wk = (const float*)d_in[6];
    const float* bk = (const float*)d_in[7];
    const float* wv = (const float*)d_in[8];
    const float* bv = (const float*)d_in[9];
    const float* wo = (const float*)d_in[10];
    const float* bo = (const float*)d_in[11];
    float* out = (float*)d_out;

    char* ws = (char*)d_ws;
    const size_t XB = (size_t)4096 * 1024 * 2;  // 8 MB bf16 activation
    const size_t WB = (size_t)1024 * 1024 * 2;  // 2 MB bf16 weight
    u16* xq = (u16*)(ws);
    u16* xk = (u16*)(ws + XB);        // after qkv: O-half 0
    u16* xv = (u16*)(ws + 2 * XB);    // after qkv: O-half 1
    u16* wqb = (u16*)(ws + 3 * XB);
    u16* wkb = (u16*)(ws + 3 * XB + WB);
    u16* wvb = (u16*)(ws + 3 * XB + 2 * WB);
    u16* wob = (u16*)(ws + 3 * XB + 3 * WB);
    u16* Qb = (u16*)(ws + 3 * XB + 4 * WB);
    u16* Kb = (u16*)(ws + 4 * XB + 4 * WB);
    u16* VTb = (u16*)(ws + 5 * XB + 4 * WB);
    u64* bits = (u64*)(ws + 6 * XB + 4 * WB);
    float* Lbuf = (float*)(ws + 6 * XB + 4 * WB + (512 << 10));
    u16* Opart = xk;    // 16 MB spanning xk+xv (dead after gemm_qkv)
    u16* Xattn = xq;    // xq dead after gemm_qkv

    prep<<<20480, 256, 0, stream>>>(query, key_, value, wq, wk, wv, wo, mask,
                                    xq, xk, xv, wqb, wkb, wvb, wob, bits);
    gemm_qkv<<<768, 256, 0, stream>>>(xq, xk, xv, wqb, wkb, wvb,
                                      bq, bk, bv, Qb, Kb, VTb);
    attn_kernel<<<dim3(16, 16, 8), 256, 0, stream>>>(Qb, Kb, VTb, bits, Opart, Lbuf);
    merge_halves<<<2048, 256, 0, stream>>>(Opart, Lbuf, Xattn);
    gemm_out<<<512, 256, 0, stream>>>(Xattn, wob, bo, out);
}

// Round 12
// 222.161 us; speedup vs baseline: 1.0850x; 1.0617x over previous
//
#include <hip/hip_runtime.h>

// MHA: B=4, S=1024, D=1024, H=16, DK=64
// prep (cvt+mask[b][kt][q]) -> fused QKV GEMM (global-swizzled global_load_lds)
// -> flash attn KV-split x2, S^T trick (operand-swapped QK^T -> packed b64 P
// stores, 1 mask load/tile, scalar l) -> merge -> out GEMM.

typedef __attribute__((ext_vector_type(8))) short short8;
typedef __attribute__((ext_vector_type(4))) float f32x4;
typedef __attribute__((ext_vector_type(4))) unsigned short u16x4;
typedef unsigned short u16;
typedef unsigned long long u64;

#define SCALE_Q 0.180336880f  // 0.125 * log2(e); folded into Q at projection

__device__ __forceinline__ u16 f2bf(float f) {  // RNE
    unsigned u = __float_as_uint(f);
    return (u16)((u + 0x7FFFu + ((u >> 16) & 1u)) >> 16);
}
__device__ __forceinline__ u16 f2bf_fast(float f) {  // round-half-up
    return (u16)((__float_as_uint(f) + 0x8000u) >> 16);
}
__device__ __forceinline__ float bf2f(u16 v) {
    return __uint_as_float((unsigned)v << 16);
}

// async global->LDS, 16B per lane; LDS dest is wave-uniform base + lane*16
__device__ __forceinline__ void gl_lds16(const u16* g, u16* l) {
    __builtin_amdgcn_global_load_lds(
        (__attribute__((address_space(1))) void*)g,
        (__attribute__((address_space(3))) void*)l, 16, 0, 0);
}

// ---------------- fused prep: 7x f32->bf16 cvt + mask->bits ----------------
__global__ __launch_bounds__(256) void prep(
    const float* __restrict__ q, const float* __restrict__ k,
    const float* __restrict__ v, const float* __restrict__ wq,
    const float* __restrict__ wk, const float* __restrict__ wv,
    const float* __restrict__ wo, const int* __restrict__ mask,
    u16* __restrict__ xq, u16* __restrict__ xk, u16* __restrict__ xv,
    u16* __restrict__ wqb, u16* __restrict__ wkb, u16* __restrict__ wvb,
    u16* __restrict__ wob, u64* __restrict__ bits) {
    int bid = blockIdx.x;
    if (bid < 16384) {
        const float* src; u16* dst; int i;
        if (bid < 12288) {
            int chunk = bid >> 12;
            int off = bid & 4095;
            src = (chunk == 0) ? q : ((chunk == 1) ? k : v);
            dst = (chunk == 0) ? xq : ((chunk == 1) ? xk : xv);
            i = off * 256 + threadIdx.x;
        } else {
            int wb = bid - 12288;
            int chunk = wb >> 10;
            int off = wb & 1023;
            src = (chunk == 0) ? wq : ((chunk == 1) ? wk : ((chunk == 2) ? wv : wo));
            dst = (chunk == 0) ? wqb : ((chunk == 1) ? wkb : ((chunk == 2) ? wvb : wob));
            i = off * 256 + threadIdx.x;
        }
        f32x4 val = ((const f32x4*)src)[i];
        u16x4 r;
        r.x = f2bf(val.x); r.y = f2bf(val.y); r.z = f2bf(val.z); r.w = f2bf(val.w);
        ((u16x4*)dst)[i] = r;
    } else {
        int mb = bid - 16384;   // 0..4095
        int wid = threadIdx.x >> 6, lane = threadIdx.x & 63;
        int base = mb * 1024 + wid * 256;
        int b = mb >> 10, qrow = mb & 1023;
        #pragma unroll
        for (int j = 0; j < 4; ++j) {
            u64 bal = __ballot(mask[base + j * 64 + lane] != 0);
            int kt = wid * 4 + j;
            if (lane == 0) bits[(size_t)(b * 16 + kt) * 1024 + qrow] = bal;  // [b][kt][q]
        }
    }
}

// ---------------- fused QKV projection GEMM (128x128, swizzled staging) -----
__global__ __launch_bounds__(256, 3) void gemm_qkv(
    const u16* __restrict__ Aq, const u16* __restrict__ Ak, const u16* __restrict__ Av,
    const u16* __restrict__ Wq, const u16* __restrict__ Wk, const u16* __restrict__ Wv,
    const float* __restrict__ bq, const float* __restrict__ bk, const float* __restrict__ bv,
    u16* __restrict__ Qo, u16* __restrict__ Ko, u16* __restrict__ VTo) {
    __shared__ __align__(16) u16 As[128 * 64];
    __shared__ __align__(16) u16 Bs[128 * 64];
    const int id = blockIdx.x;
    const int n0 = (id / 96) * 128;
    const int pm = id % 96;
    const int p = pm >> 5;
    const int m0 = (pm & 31) * 128;
    const u16* A = (p == 0) ? Aq : ((p == 1) ? Ak : Av);
    const u16* W = (p == 0) ? Wq : ((p == 1) ? Wk : Wv);
    const float* bias = (p == 0) ? bq : ((p == 1) ? bk : bv);

    const int t = threadIdx.x;
    const int lane = t & 63;
    const int wid = t >> 6;
    const int l15 = lane & 15;
    const int quad = lane >> 4;
    const int wm = (wid & 1) * 64;
    const int wn = (wid >> 1) * 64;
    const int r8 = lane >> 3, gr = lane & 7;
    const int gsw = (gr ^ r8) * 8;   // swizzled global granule offset

    f32x4 acc[4][4];
    #pragma unroll
    for (int i = 0; i < 4; ++i)
        #pragma unroll
        for (int j = 0; j < 4; ++j) acc[i][j] = (f32x4){0.f, 0.f, 0.f, 0.f};

    for (int kt = 0; kt < 1024; kt += 64) {
        __syncthreads();
        #pragma unroll
        for (int c = 0; c < 8; ++c) {
            int call = wid * 8 + c;
            if (call < 16) {
                int rb = call * 8;
                gl_lds16(&A[(size_t)(m0 + rb + r8) * 1024 + kt + gsw], &As[rb * 64]);
            } else {
                int rb = (call - 16) * 8;
                gl_lds16(&W[(size_t)(n0 + rb + r8) * 1024 + kt + gsw], &Bs[rb * 64]);
            }
        }
        __syncthreads();
        #pragma unroll
        for (int ks = 0; ks < 2; ++ks) {
            short8 af[4], bf[4];
            #pragma unroll
            for (int i = 0; i < 4; ++i) {
                int mr = wm + i * 16 + l15;
                af[i] = *(const short8*)&As[mr * 64 + (((ks << 2) + quad) ^ (mr & 7)) * 8];
                int nr = wn + i * 16 + l15;
                bf[i] = *(const short8*)&Bs[nr * 64 + (((ks << 2) + quad) ^ (nr & 7)) * 8];
            }
            #pragma unroll
            for (int mi = 0; mi < 4; ++mi)
                #pragma unroll
                for (int ni = 0; ni < 4; ++ni)
                    acc[mi][ni] = __builtin_amdgcn_mfma_f32_16x16x32_bf16(
                        af[mi], bf[ni], acc[mi][ni], 0, 0, 0);
        }
    }

    u16* dst01 = (p == 0) ? Qo : Ko;
    const float qs = (p == 0) ? SCALE_Q : 1.0f;
    #pragma unroll
    for (int mi = 0; mi < 4; ++mi) {
        #pragma unroll
        for (int ni = 0; ni < 4; ++ni) {
            int col = n0 + wn + ni * 16 + l15;  // 0..1023
            int h = col >> 6, dk = col & 63;
            float bcol = bias[col];
            if (p < 2) {
                #pragma unroll
                for (int r = 0; r < 4; ++r) {
                    int row = m0 + wm + mi * 16 + quad * 4 + r;
                    int bb = row >> 10, s = row & 1023;
                    dst01[(size_t)((bb * 16 + h) * 1024 + s) * 64 + dk] =
                        f2bf((acc[mi][ni][r] + bcol) * qs);
                }
            } else {
                int row0 = m0 + wm + mi * 16 + quad * 4;
                int bb = row0 >> 10, s0 = row0 & 1023;
                u64 pk = 0;
                #pragma unroll
                for (int r = 0; r < 4; ++r)
                    pk |= (u64)f2bf(acc[mi][ni][r] + bcol) << (16 * r);
                *(u64*)&VTo[(size_t)((bb * 16 + h) * 64 + dk) * 1024 + s0] = pk;
            }
        }
    }
}

// ---------------- output projection GEMM (64x128, swizzled staging) ---------
__global__ __launch_bounds__(256, 3) void gemm_out(
    const u16* __restrict__ X, const u16* __restrict__ Wo,
    const float* __restrict__ bo, float* __restrict__ out) {
    __shared__ __align__(16) u16 As[64 * 64];
    __shared__ __align__(16) u16 Bs[128 * 64];
    const int id = blockIdx.x;
    const int n0 = (id >> 6) * 128;
    const int m0 = (id & 63) * 64;
    const int t = threadIdx.x;
    const int lane = t & 63;
    const int wid = t >> 6;
    const int l15 = lane & 15;
    const int quad = lane >> 4;
    const int wm = (wid & 1) * 32;
    const int wn = (wid >> 1) * 64;
    const int r8 = lane >> 3, gr = lane & 7;
    const int gsw = (gr ^ r8) * 8;

    f32x4 acc[2][4];
    #pragma unroll
    for (int i = 0; i < 2; ++i)
        #pragma unroll
        for (int j = 0; j < 4; ++j) acc[i][j] = (f32x4){0.f, 0.f, 0.f, 0.f};

    for (int kt = 0; kt < 1024; kt += 64) {
        __syncthreads();
        #pragma unroll
        for (int c = 0; c < 6; ++c) {
            int call = wid * 6 + c;
            if (call < 8) {
                int rb = call * 8;
                gl_lds16(&X[(size_t)(m0 + rb + r8) * 1024 + kt + gsw], &As[rb * 64]);
            } else {
                int rb = (call - 8) * 8;
                gl_lds16(&Wo[(size_t)(n0 + rb + r8) * 1024 + kt + gsw], &Bs[rb * 64]);
            }
        }
        __syncthreads();
        #pragma unroll
        for (int ks = 0; ks < 2; ++ks) {
            short8 af[2], bf[4];
            #pragma unroll
            for (int i = 0; i < 2; ++i) {
                int mr = wm + i * 16 + l15;
                af[i] = *(const short8*)&As[mr * 64 + (((ks << 2) + quad) ^ (mr & 7)) * 8];
            }
            #pragma unroll
            for (int j = 0; j < 4; ++j) {
                int nr = wn + j * 16 + l15;
                bf[j] = *(const short8*)&Bs[nr * 64 + (((ks << 2) + quad) ^ (nr & 7)) * 8];
            }
            #pragma unroll
            for (int mi = 0; mi < 2; ++mi)
                #pragma unroll
                for (int ni = 0; ni < 4; ++ni)
                    acc[mi][ni] = __builtin_amdgcn_mfma_f32_16x16x32_bf16(
                        af[mi], bf[ni], acc[mi][ni], 0, 0, 0);
        }
    }

    #pragma unroll
    for (int mi = 0; mi < 2; ++mi) {
        #pragma unroll
        for (int ni = 0; ni < 4; ++ni) {
            int col = n0 + wn + ni * 16 + l15;
            float bcol = bo[col];
            #pragma unroll
            for (int r = 0; r < 4; ++r) {
                int row = m0 + wm + mi * 16 + quad * 4 + r;
                out[(size_t)row * 1024 + col] = acc[mi][ni][r] + bcol;
            }
        }
    }
}

// ---------------- flash attention, KV-split x2, S^T trick -------------------
// grid (16 qt, 16 h, 8 = b*2+half). Wave computes S^T = K·Q^T: lane holds
// q=l15 fixed, kv=mi*16+quad*4+r -> P stores pack to ds_write_b64, one mask
// u64 per tile per lane, scalar l per lane.
__global__ __launch_bounds__(256) void attn_kernel(
    const u16* __restrict__ Q, const u16* __restrict__ K, const u16* __restrict__ VT,
    const u64* __restrict__ mbits, u16* __restrict__ O, float* __restrict__ L) {
    __shared__ __align__(16) u16 Ks[64 * 64];
    __shared__ __align__(16) u16 Vs[64 * 64];
    __shared__ __align__(16) u16 Ps[4][16 * 72];  // per-wave P [q][kv], stride 72

    const int qt = blockIdx.x;
    const int h = blockIdx.y;
    const int b = blockIdx.z >> 1;
    const int half = blockIdx.z & 1;
    const int t = threadIdx.x;
    const int lane = t & 63;
    const int wid = t >> 6;
    const int l15 = lane & 15;
    const int quad = lane >> 4;
    const int q0 = qt * 64;
    const int sr = t >> 3;
    const int sc = t & 7;
    const int ktg0 = half * 8;   // first global kv tile of this half

    const size_t headoff = (size_t)(b * 16 + h) * 1024 * 64;
    const u16* Qh = Q + headoff;
    const u16* Kh = K + headoff;
    const u16* Vh = VT + headoff;  // [64][1024]

    // Q fragments in registers (q-row = q0 + wid*16 + l15); same mapping for
    // A- and B-frags, so the S^T operand swap needs no load changes.
    short8 qf[2];
    #pragma unroll
    for (int ks = 0; ks < 2; ++ks)
        qf[ks] = *(const short8*)&Qh[(size_t)(q0 + wid * 16 + l15) * 64 + ks * 32 + quad * 8];

    f32x4 o_acc[4];
    #pragma unroll
    for (int j = 0; j < 4; ++j) o_acc[j] = (f32x4){0.f, 0.f, 0.f, 0.f};
    float lacc = 0.f;   // per-lane: q = l15, this lane's kv subset

    // transposed mask [b][kt][q]: one u64 per tile for this lane's q-row
    const u64* mbase = &mbits[(size_t)(b * 16) * 1024 + q0 + wid * 16 + l15];

    // preload first kv tile of this half
    short8 kpre[2], vpre[2];
    #pragma unroll
    for (int p = 0; p < 2; ++p) {
        int r = p * 32 + sr;
        kpre[p] = *(const short8*)&Kh[(size_t)(ktg0 * 64 + r) * 64 + sc * 8];
        vpre[p] = *(const short8*)&Vh[(size_t)r * 1024 + ktg0 * 64 + sc * 8];
    }

    for (int kt = 0; kt < 8; ++kt) {
        __syncthreads();
        #pragma unroll
        for (int p = 0; p < 2; ++p) {
            int r = p * 32 + sr;
            int gl = sc ^ (r & 7);
            *(short8*)&Ks[r * 64 + gl * 8] = kpre[p];
            *(short8*)&Vs[r * 64 + gl * 8] = vpre[p];
        }
        __syncthreads();

        // prefetch next kv tile of this half
        if (kt < 7) {
            int kvn = (ktg0 + kt + 1) * 64;
            #pragma unroll
            for (int p = 0; p < 2; ++p) {
                int r = p * 32 + sr;
                kpre[p] = *(const short8*)&Kh[(size_t)(kvn + r) * 64 + sc * 8];
                vpre[p] = *(const short8*)&Vh[(size_t)r * 1024 + kvn + sc * 8];
            }
        }

        // S^T = K Q^T : sacc[mi] rows kv=mi*16+quad*4+r, col q=l15
        f32x4 sacc[4];
        #pragma unroll
        for (int j = 0; j < 4; ++j) sacc[j] = (f32x4){0.f, 0.f, 0.f, 0.f};
        #pragma unroll
        for (int ks = 0; ks < 2; ++ks) {
            #pragma unroll
            for (int mi = 0; mi < 4; ++mi) {
                int n = mi * 16 + l15;
                short8 kf = *(const short8*)&Ks[n * 64 + (((ks << 2) + quad) ^ (n & 7)) * 8];
                sacc[mi] = __builtin_amdgcn_mfma_f32_16x16x32_bf16(kf, qf[ks], sacc[mi], 0, 0, 0);
            }
        }

        // masked exp2; pack 4 bf16 -> one ds_write_b64 per mi
        u64 w = mbase[(size_t)(ktg0 + kt) * 1024];
        unsigned t0 = (unsigned)(w >> (quad * 4));
        unsigned t1 = (unsigned)(w >> (quad * 4 + 32));
        #pragma unroll
        for (int mi = 0; mi < 4; ++mi) {
            unsigned sel = (mi & 2) ? t1 : t0;
            sel >>= (mi & 1) * 16;
            u64 pk = 0;
            #pragma unroll
            for (int r = 0; r < 4; ++r) {
                float p = __builtin_amdgcn_exp2f(sacc[mi][r]);
                p = ((sel >> r) & 1u) ? p : 0.f;
                lacc += p;
                pk |= (u64)f2bf_fast(p) << (16 * r);
            }
            *(u64*)&Ps[wid][l15 * 72 + mi * 16 + quad * 4] = pk;
        }

        // O += P V (P per-wave LDS A-layout; V^T B-layout)
        #pragma unroll
        for (int ks = 0; ks < 2; ++ks) {
            short8 pf = *(const short8*)&Ps[wid][l15 * 72 + ks * 32 + quad * 8];
            #pragma unroll
            for (int j = 0; j < 4; ++j) {
                int d = j * 16 + l15;
                short8 vf = *(const short8*)&Vs[d * 64 + (((ks << 2) + quad) ^ (d & 7)) * 8];
                o_acc[j] = __builtin_amdgcn_mfma_f32_16x16x32_bf16(pf, vf, o_acc[j], 0, 0, 0);
            }
        }
    }

    // reduce l across the 4 lanes sharing q=l15, store partials
    float l = lacc;
    l += __shfl_xor(l, 16);
    l += __shfl_xor(l, 32);
    u16* Oh = O + (size_t)half * 4194304;
    float* Lh = L + (size_t)half * 65536;
    if (lane < 16)
        Lh[(size_t)(b * 16 + h) * 1024 + q0 + wid * 16 + lane] = l;
    #pragma unroll
    for (int r = 0; r < 4; ++r) {
        int qrow = q0 + wid * 16 + quad * 4 + r;   // o_acc row (C-layout)
        #pragma unroll
        for (int ni = 0; ni < 4; ++ni) {
            Oh[(size_t)(b * 1024 + qrow) * 1024 + h * 64 + ni * 16 + l15] =
                f2bf(o_acc[ni][r]);
        }
    }
}

// ---------------- merge: X = (o0 + o1) / (l0 + l1), bf16 out ----------------
__global__ __launch_bounds__(256) void merge_halves(
    const u16* __restrict__ O, const float* __restrict__ L, u16* __restrict__ X) {
    int i = (blockIdx.x * 256 + threadIdx.x) * 8;   // elem index, 8 per thread
    int b = i >> 20, s = (i >> 10) & 1023, c = i & 1023, h = c >> 6;
    short8 o0 = *(const short8*)&O[i];
    short8 o1 = *(const short8*)&O[4194304 + i];
    size_t li = (size_t)(b * 16 + h) * 1024 + s;
    float inv = 1.0f / (L[li] + L[65536 + li]);
    short8 r;
    #pragma unroll
    for (int j = 0; j < 8; ++j) {
        float x = (bf2f((u16)o0[j]) + bf2f((u16)o1[j])) * inv;
        r[j] = (short)f2bf(x);
    }
    *(short8*)&X[i] = r;
}

// ---------------- launch ----------------
extern "C" void kernel_launch(void* const* d_in, const int* in_sizes, int n_in,
                              void* d_out, int out_size, void* d_ws, size_t ws_size,
                              hipStream_t stream) {
    const float* query = (const float*)d_in[0];
    const float* key_ = (const float*)d_in[1];
    const float* value = (const float*)d_in[2];
    const int* mask = (const int*)d_in[3];
    const float* wq = (const float*)d_in[4];
    const float* bq = (const float*)d_in[5];
    const float* wk = (const float*)d_in[6];
    const float* bk = (const float*)d_in[7];
    const float* wv = (const float*)d_in[8];
    const float* bv = (const float*)d_in[9];
    const float* wo = (const float*)d_in[10];
    const float* bo = (const float*)d_in[11];
    float* out = (float*)d_out;

    char* ws = (char*)d_ws;
    const size_t XB = (size_t)4096 * 1024 * 2;  // 8 MB bf16 activation
    const size_t WB = (size_t)1024 * 1024 * 2;  // 2 MB bf16 weight
    u16* xq = (u16*)(ws);
    u16* xk = (u16*)(ws + XB);        // after qkv: O-half 0
    u16* xv = (u16*)(ws + 2 * XB);    // after qkv: O-half 1
    u16* wqb = (u16*)(ws + 3 * XB);
    u16* wkb = (u16*)(ws + 3 * XB + WB);
    u16* wvb = (u16*)(ws + 3 * XB + 2 * WB);
    u16* wob = (u16*)(ws + 3 * XB + 3 * WB);
    u16* Qb = (u16*)(ws + 3 * XB + 4 * WB);
    u16* Kb = (u16*)(ws + 4 * XB + 4 * WB);
    u16* VTb = (u16*)(ws + 5 * XB + 4 * WB);
    u64* bits = (u64*)(ws + 6 * XB + 4 * WB);
    float* Lbuf = (float*)(ws + 6 * XB + 4 * WB + (512 << 10));
    u16* Opart = xk;    // 16 MB spanning xk+xv (dead after gemm_qkv)
    u16* Xattn = xq;    // xq dead after gemm_qkv

    prep<<<20480, 256, 0, stream>>>(query, key_, value, wq, wk, wv, wo, mask,
                                    xq, xk, xv, wqb, wkb, wvb, wob, bits);
    gemm_qkv<<<768, 256, 0, stream>>>(xq, xk, xv, wqb, wkb, wvb,
                                      bq, bk, bv, Qb, Kb, VTb);
    attn_kernel<<<dim3(16, 16, 8), 256, 0, stream>>>(Qb, Kb, VTb, bits, Opart, Lbuf);
    merge_halves<<<2048, 256, 0, stream>>>(Opart, Lbuf, Xattn);
    gemm_out<<<512, 256, 0, stream>>>(Xattn, wob, bo, out);
}